// Round 1
// baseline (785.840 us; speedup 1.0000x reference)
//
#include <hip/hip_runtime.h>
#include <hip/hip_bf16.h>

#define D_FEAT 64

// One 64-lane wave per edge; lane = feature index.
// gather x[col] (256B coalesced), scale, atomicAdd into out[row] (256B coalesced).
__global__ __launch_bounds__(256) void spmm_atomic_kernel(
    const float* __restrict__ x,
    const int*   __restrict__ edge_row,
    const int*   __restrict__ edge_col,
    const float* __restrict__ edge_val,
    float*       __restrict__ out,
    int n_edges)
{
    const int gtid   = blockIdx.x * blockDim.x + threadIdx.x;
    const int wave   = gtid >> 6;          // global wave id = edge id
    const int lane   = threadIdx.x & 63;   // feature index

    if (wave >= n_edges) return;

    const int   r = edge_row[wave];
    const int   c = edge_col[wave];
    const float v = edge_val[wave];

    const float xv = x[(size_t)c * D_FEAT + lane];
    atomicAdd(&out[(size_t)r * D_FEAT + lane], v * xv);
}

extern "C" void kernel_launch(void* const* d_in, const int* in_sizes, int n_in,
                              void* d_out, int out_size, void* d_ws, size_t ws_size,
                              hipStream_t stream)
{
    // setup_inputs order: t, x, edge_row, edge_col, edge_val
    const float* x        = (const float*)d_in[1];
    const int*   edge_row = (const int*)d_in[2];
    const int*   edge_col = (const int*)d_in[3];
    const float* edge_val = (const float*)d_in[4];
    float*       out      = (float*)d_out;

    const int n_edges = in_sizes[2];

    // d_out is poisoned with 0xAA before every launch — zero it (capture-safe).
    hipMemsetAsync(out, 0, (size_t)out_size * sizeof(float), stream);

    // one wave (64 lanes) per edge, 4 waves per 256-thread block
    const int waves_per_block = 256 / 64;
    const int n_blocks = (n_edges + waves_per_block - 1) / waves_per_block;
    spmm_atomic_kernel<<<n_blocks, 256, 0, stream>>>(
        x, edge_row, edge_col, edge_val, out, n_edges);
}

// Round 2
// 601.539 us; speedup vs baseline: 1.3064x; 1.3064x over previous
//
#include <hip/hip_runtime.h>
#include <hip/hip_bf16.h>

#define D 64
#define SCAN_BLOCK 256

// ---------------- fallback: round-1 atomic kernel ----------------
__global__ __launch_bounds__(256) void spmm_atomic_kernel(
    const float* __restrict__ x,
    const int*   __restrict__ edge_row,
    const int*   __restrict__ edge_col,
    const float* __restrict__ edge_val,
    float*       __restrict__ out,
    int n_edges)
{
    const int gtid = blockIdx.x * blockDim.x + threadIdx.x;
    const int wave = gtid >> 6;
    const int lane = threadIdx.x & 63;
    if (wave >= n_edges) return;
    const int   r = edge_row[wave];
    const int   c = edge_col[wave];
    const float v = edge_val[wave];
    atomicAdd(&out[(size_t)r * D + lane], v * x[(size_t)c * D + lane]);
}

// ---------------- CSR build ----------------
__global__ void hist_kernel(const int* __restrict__ rows, int* __restrict__ counts,
                            int n_edges)
{
    int i = blockIdx.x * blockDim.x + threadIdx.x;
    int stride = gridDim.x * blockDim.x;
    for (; i < n_edges; i += stride)
        atomicAdd(&counts[rows[i]], 1);
}

// per-block partial sums of counts
__global__ void scan_partial_kernel(const int* __restrict__ counts,
                                    int* __restrict__ partials, int n)
{
    __shared__ int s[SCAN_BLOCK];
    int i = blockIdx.x * SCAN_BLOCK + threadIdx.x;
    s[threadIdx.x] = (i < n) ? counts[i] : 0;
    __syncthreads();
    for (int off = SCAN_BLOCK / 2; off > 0; off >>= 1) {
        if (threadIdx.x < off) s[threadIdx.x] += s[threadIdx.x + off];
        __syncthreads();
    }
    if (threadIdx.x == 0) partials[blockIdx.x] = s[0];
}

// exclusive scan of up to 1024 partials, single block of 1024 threads
__global__ void scan_top_kernel(int* partials, int nparts)
{
    __shared__ int s[1024];
    int t = threadIdx.x;
    int mine = (t < nparts) ? partials[t] : 0;
    s[t] = mine;
    for (int off = 1; off < 1024; off <<= 1) {
        __syncthreads();
        int v = (t >= off) ? s[t - off] : 0;
        __syncthreads();
        s[t] += v;
    }
    if (t < nparts) partials[t] = s[t] - mine;  // exclusive
}

// in-place: counts -> exclusive offsets (+ copy into cursor)
__global__ void scan_final_kernel(int* __restrict__ counts_offsets,
                                  int* __restrict__ cursor,
                                  const int* __restrict__ partials,
                                  int n, int n_nodes)
{
    __shared__ int s[SCAN_BLOCK];
    int t = threadIdx.x;
    int i = blockIdx.x * SCAN_BLOCK + t;
    int mine = (i < n) ? counts_offsets[i] : 0;
    s[t] = mine;
    for (int off = 1; off < SCAN_BLOCK; off <<= 1) {
        __syncthreads();
        int v = (t >= off) ? s[t - off] : 0;
        __syncthreads();
        s[t] += v;
    }
    int excl = s[t] - mine + partials[blockIdx.x];
    if (i < n) {
        counts_offsets[i] = excl;
        if (i < n_nodes) cursor[i] = excl;
    }
}

__global__ void scatter_kernel(const int* __restrict__ rows,
                               const int* __restrict__ cols,
                               const float* __restrict__ vals,
                               int* __restrict__ cursor,
                               int* __restrict__ col_s,
                               float* __restrict__ val_s,
                               int n_edges)
{
    int i = blockIdx.x * blockDim.x + threadIdx.x;
    int stride = gridDim.x * blockDim.x;
    for (; i < n_edges; i += stride) {
        int r = rows[i];
        int pos = atomicAdd(&cursor[r], 1);
        col_s[pos] = cols[i];
        val_s[pos] = vals[i];
    }
}

// ---------------- CSR SpMM: one wave per row, lane = feature ----------------
__global__ __launch_bounds__(256) void spmm_csr_kernel(
    const float* __restrict__ x,
    const int*   __restrict__ offsets,
    const int*   __restrict__ col_s,
    const float* __restrict__ val_s,
    float*       __restrict__ out,
    int n_nodes)
{
    const int wave_in_block = threadIdx.x >> 6;
    const int lane          = threadIdx.x & 63;
    const int row           = blockIdx.x * 4 + wave_in_block;
    if (row >= n_nodes) return;

    const int start = offsets[row];
    const int end   = offsets[row + 1];

    float acc = 0.f;
    int j = start;
    for (; j + 4 <= end; j += 4) {
        const int   c0 = col_s[j + 0]; const float v0 = val_s[j + 0];
        const int   c1 = col_s[j + 1]; const float v1 = val_s[j + 1];
        const int   c2 = col_s[j + 2]; const float v2 = val_s[j + 2];
        const int   c3 = col_s[j + 3]; const float v3 = val_s[j + 3];
        acc += v0 * x[(size_t)c0 * D + lane];
        acc += v1 * x[(size_t)c1 * D + lane];
        acc += v2 * x[(size_t)c2 * D + lane];
        acc += v3 * x[(size_t)c3 * D + lane];
    }
    for (; j < end; ++j)
        acc += val_s[j] * x[(size_t)col_s[j] * D + lane];

    out[(size_t)row * D + lane] = acc;
}

static inline size_t align16(size_t v) { return (v + 15) & ~(size_t)15; }

extern "C" void kernel_launch(void* const* d_in, const int* in_sizes, int n_in,
                              void* d_out, int out_size, void* d_ws, size_t ws_size,
                              hipStream_t stream)
{
    // setup_inputs order: t, x, edge_row, edge_col, edge_val
    const float* x        = (const float*)d_in[1];
    const int*   edge_row = (const int*)d_in[2];
    const int*   edge_col = (const int*)d_in[3];
    const float* edge_val = (const float*)d_in[4];
    float*       out      = (float*)d_out;

    const int n_edges = in_sizes[2];
    const int n_nodes = out_size / D;

    // workspace carve
    const size_t off_offsets = 0;                                         // (n_nodes+1) ints
    const size_t off_cursor  = align16(off_offsets + (size_t)(n_nodes + 1) * 4); // n_nodes ints
    const size_t off_cols    = align16(off_cursor + (size_t)n_nodes * 4); // n_edges ints
    const size_t off_vals    = align16(off_cols + (size_t)n_edges * 4);   // n_edges floats
    const size_t off_parts   = align16(off_vals + (size_t)n_edges * 4);   // <=1024 ints
    const size_t ws_needed   = off_parts + 1024 * 4;

    const int nscan   = n_nodes + 1;
    const int nparts  = (nscan + SCAN_BLOCK - 1) / SCAN_BLOCK;

    if (ws_size < ws_needed || nparts > 1024) {
        // fallback: atomic scatter (round-1 kernel)
        hipMemsetAsync(out, 0, (size_t)out_size * sizeof(float), stream);
        const int waves_per_block = 256 / 64;
        const int n_blocks = (n_edges + waves_per_block - 1) / waves_per_block;
        spmm_atomic_kernel<<<n_blocks, 256, 0, stream>>>(
            x, edge_row, edge_col, edge_val, out, n_edges);
        return;
    }

    char* ws = (char*)d_ws;
    int*   offsets = (int*)(ws + off_offsets);
    int*   cursor  = (int*)(ws + off_cursor);
    int*   col_s   = (int*)(ws + off_cols);
    float* val_s   = (float*)(ws + off_vals);
    int*   parts   = (int*)(ws + off_parts);

    // 1. zero counts
    hipMemsetAsync(offsets, 0, (size_t)nscan * sizeof(int), stream);

    // 2. histogram rows
    {
        int blocks = (n_edges + 255) / 256;
        if (blocks > 16384) blocks = 16384;
        hist_kernel<<<blocks, 256, 0, stream>>>(edge_row, offsets, n_edges);
    }

    // 3. blocked exclusive scan: counts -> offsets (in place), copy to cursor
    scan_partial_kernel<<<nparts, SCAN_BLOCK, 0, stream>>>(offsets, parts, nscan);
    scan_top_kernel<<<1, 1024, 0, stream>>>(parts, nparts);
    scan_final_kernel<<<nparts, SCAN_BLOCK, 0, stream>>>(offsets, cursor, parts, nscan, n_nodes);

    // 4. scatter (col,val) into row-sorted order
    {
        int blocks = (n_edges + 255) / 256;
        if (blocks > 16384) blocks = 16384;
        scatter_kernel<<<blocks, 256, 0, stream>>>(
            edge_row, edge_col, edge_val, cursor, col_s, val_s, n_edges);
    }

    // 5. CSR SpMM: one wave per row
    {
        int blocks = (n_nodes + 3) / 4;
        spmm_csr_kernel<<<blocks, 256, 0, stream>>>(
            x, offsets, col_s, val_s, out, n_nodes);
    }
}